// Round 1
// baseline (774.672 us; speedup 1.0000x reference)
//
#include <hip/hip_runtime.h>
#include <hip/hip_bf16.h>

// Sparse GAT layer:
//   h = X @ W                                  [N,128]
//   s1[n] = h[n]·a[:128], s2[n] = h[n]·a[128:] (factorized edge score)
//   edge_e = exp(leakyrelu(s1[src]+s2[dst], 0.2))
//   rowsum[src] += edge_e ; h_prime[src] += edge_e * h[dst]   (atomics)
//   out = elu(h_prime / rowsum)
//
// h_prime accumulates directly in d_out (zeroed via hipMemsetAsync each call).

constexpr int D  = 128;
constexpr int TM = 32;   // rows per block in GEMM
constexpr int KP = 32;   // k-panel

__global__ __launch_bounds__(256) void gemm_h(const float* __restrict__ X,
                                              const float* __restrict__ W,
                                              float* __restrict__ h, int N) {
    __shared__ float Ws[KP][D];       // 16 KB
    __shared__ float Xs[TM][KP + 1];  // padded, ~4.1 KB
    const int tid  = threadIdx.x;
    const int row0 = blockIdx.x * TM;
    const int j    = tid & (D - 1);   // output column
    const int rg   = tid >> 7;        // row group 0/1 (16 rows each)

    float acc[16];
#pragma unroll
    for (int r = 0; r < 16; ++r) acc[r] = 0.f;

    for (int k0 = 0; k0 < D; k0 += KP) {
        // stage W panel: KP*D floats
        for (int i = tid; i < KP * D; i += 256)
            Ws[i >> 7][i & (D - 1)] = W[(k0 + (i >> 7)) * D + (i & (D - 1))];
        // stage X panel: TM*KP floats
        for (int i = tid; i < TM * KP; i += 256) {
            int r = i >> 5, c = i & 31;
            int row = row0 + r;
            Xs[r][c] = (row < N) ? X[row * D + k0 + c] : 0.f;
        }
        __syncthreads();
#pragma unroll 4
        for (int kk = 0; kk < KP; ++kk) {
            float w = Ws[kk][j];   // 2-way LDS aliasing across wave64 = free
#pragma unroll
            for (int r = 0; r < 16; ++r)
                acc[r] += Xs[rg * 16 + r][kk] * w;   // broadcast read
        }
        __syncthreads();
    }
#pragma unroll
    for (int r = 0; r < 16; ++r) {
        int row = row0 + rg * 16 + r;
        if (row < N) h[row * D + j] = acc[r];
    }
}

// one wave per node: s1[n] = h[n]·a[0:128], s2[n] = h[n]·a[128:256]
__global__ __launch_bounds__(256) void node_scores(const float* __restrict__ h,
                                                   const float* __restrict__ a,
                                                   float* __restrict__ s1,
                                                   float* __restrict__ s2, int N) {
    const int n    = blockIdx.x * 4 + (threadIdx.x >> 6);
    const int lane = threadIdx.x & 63;
    if (n >= N) return;
    const float2* h2 = (const float2*)(h + (size_t)n * D);
    const float2* a1 = (const float2*)a;
    const float2* a2 = (const float2*)(a + D);
    float2 hv = h2[lane];
    float2 v1 = a1[lane];
    float2 v2 = a2[lane];
    float p1 = hv.x * v1.x + hv.y * v1.y;
    float p2 = hv.x * v2.x + hv.y * v2.y;
#pragma unroll
    for (int off = 32; off > 0; off >>= 1) {
        p1 += __shfl_xor(p1, off);
        p2 += __shfl_xor(p2, off);
    }
    if (lane == 0) { s1[n] = p1; s2[n] = p2; }
}

// one wave per edge: atomically scatter e*h[dst] into h_prime[src]
__global__ __launch_bounds__(256) void edge_aggregate(
    const int* __restrict__ src, const int* __restrict__ dst,
    const float* __restrict__ s1, const float* __restrict__ s2,
    const float* __restrict__ h, float* __restrict__ hp,
    float* __restrict__ rowsum, int E) {
    const int e    = blockIdx.x * 4 + (threadIdx.x >> 6);
    const int lane = threadIdx.x & 63;
    if (e >= E) return;
    const int s = src[e];
    const int d = dst[e];
    float sc = s1[s] + s2[d];
    sc = sc > 0.f ? sc : 0.2f * sc;       // LeakyReLU(0.2)
    const float ee = __expf(sc);
    const float2* hd = (const float2*)(h + (size_t)d * D);
    float2 hv = hd[lane];
    float* o = hp + (size_t)s * D + lane * 2;
    atomicAdd(o,     ee * hv.x);
    atomicAdd(o + 1, ee * hv.y);
    if (lane == 0) atomicAdd(rowsum + s, ee);
}

// in-place: out = elu(out / rowsum[row])
__global__ __launch_bounds__(256) void finalize(float* __restrict__ hp,
                                                const float* __restrict__ rowsum,
                                                int total) {
    const int i = blockIdx.x * 256 + threadIdx.x;
    if (i >= total) return;
    float v = hp[i] / rowsum[i >> 7];
    hp[i] = v > 0.f ? v : expm1f(v);
}

extern "C" void kernel_launch(void* const* d_in, const int* in_sizes, int n_in,
                              void* d_out, int out_size, void* d_ws, size_t ws_size,
                              hipStream_t stream) {
    const float* X    = (const float*)d_in[0];
    const int*   edge = (const int*)d_in[1];   // [2, E] int32
    const float* W    = (const float*)d_in[2];
    const float* a    = (const float*)d_in[3];
    float* out = (float*)d_out;

    const int N = in_sizes[0] / D;
    const int E = in_sizes[1] / 2;
    const int* src = edge;
    const int* dst = edge + E;

    char* ws = (char*)d_ws;
    float* h      = (float*)ws; ws += (size_t)N * D * sizeof(float);
    float* s1     = (float*)ws; ws += (size_t)N * sizeof(float);
    float* s2     = (float*)ws; ws += (size_t)N * sizeof(float);
    float* rowsum = (float*)ws; ws += (size_t)N * sizeof(float);

    // zero the accumulators (d_out doubles as h_prime; ws is poisoned 0xAA)
    hipMemsetAsync(out, 0, (size_t)N * D * sizeof(float), stream);
    hipMemsetAsync(rowsum, 0, (size_t)N * sizeof(float), stream);

    gemm_h<<<(N + TM - 1) / TM, 256, 0, stream>>>(X, W, h, N);
    node_scores<<<(N + 3) / 4, 256, 0, stream>>>(h, a, s1, s2, N);
    edge_aggregate<<<(E + 3) / 4, 256, 0, stream>>>(src, dst, s1, s2, h, out, rowsum, E);
    finalize<<<(N * D + 255) / 256, 256, 0, stream>>>(out, rowsum, N * D);
}

// Round 2
// 346.068 us; speedup vs baseline: 2.2385x; 2.2385x over previous
//
#include <hip/hip_runtime.h>
#include <hip/hip_bf16.h>

// Sparse GAT layer, gather-based (no f32 atomics):
//   h = X @ W  (stored bf16)                       [N,128]
//   s1[n] = h[n]·a[:128], s2[n] = h[n]·a[128:]
//   CSR build by src: counts -> scan -> scatter (dst, ee) pairs
//   per-node wave gather: h' = sum ee*h[dst], rs = sum ee  (no atomics)
//   out = elu(h'/rs)   fused into the gather epilogue

constexpr int D  = 128;
constexpr int TM = 32;   // rows per block in GEMM
constexpr int KP = 32;   // k-panel

__global__ __launch_bounds__(256) void gemm_h(const float* __restrict__ X,
                                              const float* __restrict__ W,
                                              __hip_bfloat16* __restrict__ h, int N) {
    __shared__ float Ws[KP][D];       // 16 KB
    __shared__ float Xs[TM][KP + 1];  // padded
    const int tid  = threadIdx.x;
    const int row0 = blockIdx.x * TM;
    const int j    = tid & (D - 1);   // output column
    const int rg   = tid >> 7;        // row group 0/1 (16 rows each)

    float acc[16];
#pragma unroll
    for (int r = 0; r < 16; ++r) acc[r] = 0.f;

    for (int k0 = 0; k0 < D; k0 += KP) {
        for (int i = tid; i < KP * D; i += 256)
            Ws[i >> 7][i & (D - 1)] = W[(k0 + (i >> 7)) * D + (i & (D - 1))];
        for (int i = tid; i < TM * KP; i += 256) {
            int r = i >> 5, c = i & 31;
            int row = row0 + r;
            Xs[r][c] = (row < N) ? X[row * D + k0 + c] : 0.f;
        }
        __syncthreads();
#pragma unroll 4
        for (int kk = 0; kk < KP; ++kk) {
            float w = Ws[kk][j];
#pragma unroll
            for (int r = 0; r < 16; ++r)
                acc[r] += Xs[rg * 16 + r][kk] * w;
        }
        __syncthreads();
    }
#pragma unroll
    for (int r = 0; r < 16; ++r) {
        int row = row0 + rg * 16 + r;
        if (row < N) h[row * D + j] = __float2bfloat16(acc[r]);
    }
}

// one wave per node: s1[n] = h[n]·a[0:128], s2[n] = h[n]·a[128:256]
__global__ __launch_bounds__(256) void node_scores(const __hip_bfloat16* __restrict__ h,
                                                   const float* __restrict__ a,
                                                   float* __restrict__ s1,
                                                   float* __restrict__ s2, int N) {
    const int n    = blockIdx.x * 4 + (threadIdx.x >> 6);
    const int lane = threadIdx.x & 63;
    if (n >= N) return;
    const __hip_bfloat162* h2 = (const __hip_bfloat162*)(h + (size_t)n * D);
    const float2* a1 = (const float2*)a;
    const float2* a2 = (const float2*)(a + D);
    float2 hv = __bfloat1622float2(h2[lane]);
    float2 v1 = a1[lane];
    float2 v2 = a2[lane];
    float p1 = hv.x * v1.x + hv.y * v1.y;
    float p2 = hv.x * v2.x + hv.y * v2.y;
#pragma unroll
    for (int off = 32; off > 0; off >>= 1) {
        p1 += __shfl_xor(p1, off);
        p2 += __shfl_xor(p2, off);
    }
    if (lane == 0) { s1[n] = p1; s2[n] = p2; }
}

// histogram of src
__global__ __launch_bounds__(256) void count_edges(const int* __restrict__ src,
                                                   int* __restrict__ counts, int E) {
    const int e = blockIdx.x * 256 + threadIdx.x;
    if (e < E) atomicAdd(&counts[src[e]], 1);
}

// single-block exclusive scan: offsets[0..N], offsets[N] = total
__global__ __launch_bounds__(256) void scan_offsets(const int* __restrict__ counts,
                                                    int* __restrict__ offsets, int N) {
    __shared__ int lsum[256];
    const int t    = threadIdx.x;
    const int slab = (N + 255) / 256;
    const int lo   = min(t * slab, N);
    const int hi   = min(lo + slab, N);
    int s = 0;
    for (int i = lo; i < hi; ++i) s += counts[i];
    lsum[t] = s;
    __syncthreads();
    // Hillis-Steele inclusive scan over 256 partials
    for (int off = 1; off < 256; off <<= 1) {
        int v = (t >= off) ? lsum[t - off] : 0;
        __syncthreads();
        lsum[t] += v;
        __syncthreads();
    }
    int run = (t == 0) ? 0 : lsum[t - 1];   // exclusive prefix of this slab
    for (int i = lo; i < hi; ++i) { offsets[i] = run; run += counts[i]; }
    if (t == 255) offsets[N] = lsum[255];
}

// scatter (dst, edge_e) into CSR; consumes offsets via atomicAdd
// (post-scatter, offsets[n] == inclusive prefix == start of node n+1)
__global__ __launch_bounds__(256) void scatter_edges(
    const int* __restrict__ src, const int* __restrict__ dst,
    const float* __restrict__ s1, const float* __restrict__ s2,
    int* __restrict__ offsets, int2* __restrict__ csr, int E) {
    const int e = blockIdx.x * 256 + threadIdx.x;
    if (e >= E) return;
    const int s = src[e];
    const int d = dst[e];
    float sc = s1[s] + s2[d];
    sc = sc > 0.f ? sc : 0.2f * sc;       // LeakyReLU(0.2)
    const float ee = __expf(sc);
    const int pos = atomicAdd(&offsets[s], 1);
    csr[pos] = make_int2(d, __float_as_int(ee));
}

// one wave per node: gather-aggregate + fused rowsum-div + ELU
__global__ __launch_bounds__(256) void aggregate(
    const int2* __restrict__ csr, const int* __restrict__ offsets,
    const __hip_bfloat16* __restrict__ h, float* __restrict__ out, int N) {
    const int n    = blockIdx.x * 4 + (threadIdx.x >> 6);
    const int lane = threadIdx.x & 63;
    if (n >= N) return;
    const int beg = (n == 0) ? 0 : offsets[n - 1];
    const int end = offsets[n];
    float2 acc = make_float2(0.f, 0.f);
    float rs = 0.f;
    int k = beg;
    for (; k + 1 < end; k += 2) {
        int2 e0 = csr[k];
        int2 e1 = csr[k + 1];
        const __hip_bfloat162* p0 = (const __hip_bfloat162*)(h + (size_t)e0.x * D);
        const __hip_bfloat162* p1 = (const __hip_bfloat162*)(h + (size_t)e1.x * D);
        __hip_bfloat162 v0 = p0[lane];
        __hip_bfloat162 v1 = p1[lane];
        float ee0 = __int_as_float(e0.y);
        float ee1 = __int_as_float(e1.y);
        float2 f0 = __bfloat1622float2(v0);
        float2 f1 = __bfloat1622float2(v1);
        acc.x += ee0 * f0.x + ee1 * f1.x;
        acc.y += ee0 * f0.y + ee1 * f1.y;
        rs    += ee0 + ee1;
    }
    if (k < end) {
        int2 e0 = csr[k];
        const __hip_bfloat162* p0 = (const __hip_bfloat162*)(h + (size_t)e0.x * D);
        float2 f0 = __bfloat1622float2(p0[lane]);
        float ee0 = __int_as_float(e0.y);
        acc.x += ee0 * f0.x;
        acc.y += ee0 * f0.y;
        rs    += ee0;
    }
    // every node has a self-loop => rs > 0
    float vx = acc.x / rs;
    float vy = acc.y / rs;
    vx = vx > 0.f ? vx : expm1f(vx);
    vy = vy > 0.f ? vy : expm1f(vy);
    ((float2*)(out + (size_t)n * D))[lane] = make_float2(vx, vy);
}

extern "C" void kernel_launch(void* const* d_in, const int* in_sizes, int n_in,
                              void* d_out, int out_size, void* d_ws, size_t ws_size,
                              hipStream_t stream) {
    const float* X    = (const float*)d_in[0];
    const int*   edge = (const int*)d_in[1];   // [2, E] int32
    const float* W    = (const float*)d_in[2];
    const float* a    = (const float*)d_in[3];
    float* out = (float*)d_out;

    const int N = in_sizes[0] / D;
    const int E = in_sizes[1] / 2;
    const int* src = edge;
    const int* dst = edge + E;

    // workspace layout (16B-aligned slabs): ~19 MB total
    char* ws = (char*)d_ws;
    __hip_bfloat16* h = (__hip_bfloat16*)ws; ws += (size_t)N * D * sizeof(__hip_bfloat16); // 12.8 MB
    int2* csr    = (int2*)ws;  ws += (size_t)E * sizeof(int2);                             // 5.52 MB
    float* s1    = (float*)ws; ws += (size_t)N * sizeof(float);
    float* s2    = (float*)ws; ws += (size_t)N * sizeof(float);
    int* counts  = (int*)ws;   ws += (size_t)N * sizeof(int);
    int* offsets = (int*)ws;   ws += (size_t)(N + 1) * sizeof(int);

    hipMemsetAsync(counts, 0, (size_t)N * sizeof(int), stream);

    gemm_h<<<(N + TM - 1) / TM, 256, 0, stream>>>(X, W, h, N);
    node_scores<<<(N + 3) / 4, 256, 0, stream>>>(h, a, s1, s2, N);
    count_edges<<<(E + 255) / 256, 256, 0, stream>>>(src, counts, E);
    scan_offsets<<<1, 256, 0, stream>>>(counts, offsets, N);
    scatter_edges<<<(E + 255) / 256, 256, 0, stream>>>(src, dst, s1, s2, offsets, csr, E);
    aggregate<<<(N + 3) / 4, 256, 0, stream>>>(csr, offsets, h, out, N);
}

// Round 3
// 219.172 us; speedup vs baseline: 3.5345x; 1.5790x over previous
//
#include <hip/hip_runtime.h>
#include <hip/hip_bf16.h>

// Sparse GAT layer, gather-based (no f32 atomics on the feature matrix):
//   h = X @ W        via bf16 MFMA (X cast on the fly, W pre-packed to B-frags)
//   s1[n] = h[n]·a[:128], s2[n] = h[n]·a[128:]
//   CSR build by src: histogram -> hierarchical scan -> scatter (dst, ee)
//   per-node wave gather: h' = sum ee*h[dst], rs = sum ee
//   out = elu(h'/rs) fused into the gather epilogue

constexpr int D = 128;

typedef __attribute__((ext_vector_type(8))) short bf16x8;   // 8 bf16 = 4 VGPRs
typedef __attribute__((ext_vector_type(4))) float f32x4;

__device__ __forceinline__ short f2bf(float f) {
    unsigned u = __float_as_uint(f);
    unsigned r = (u + 0x7fffu + ((u >> 16) & 1u)) >> 16;    // RNE
    return (short)r;
}

// Pack W into B-fragment order for mfma_f32_16x16x32_bf16:
// bw[((s*8 + t)*64 + lane)*8 + j] = W[k][n],  k = s*32 + (lane>>4)*8 + j,
//                                            n = t*16 + (lane&15)
__global__ __launch_bounds__(256) void prep_w(const float* __restrict__ W,
                                              __hip_bfloat16* __restrict__ bw) {
    const int tid = blockIdx.x * 256 + threadIdx.x;   // 2048 lane-slots
    if (tid >= 2048) return;
    const int l = tid & 63, st = tid >> 6;
    const int s = st >> 3, t = st & 7;
    const int n = t * 16 + (l & 15);
    const int q = l >> 4;
#pragma unroll
    for (int j = 0; j < 8; ++j) {
        const int k = s * 32 + q * 8 + j;
        ((short*)bw)[tid * 8 + j] = f2bf(W[k * D + n]);
    }
}

// One wave = 16 rows x 128 cols. 4 k-steps x 8 n-tiles of 16x16x32 MFMA.
__global__ __launch_bounds__(256) void gemm_mfma(const float* __restrict__ X,
                                                 const __hip_bfloat16* __restrict__ bw,
                                                 __hip_bfloat16* __restrict__ h, int N) {
    const int wave = threadIdx.x >> 6, lane = threadIdx.x & 63;
    const int r0 = blockIdx.x * 64 + wave * 16;
    const int m = lane & 15, q = lane >> 4;
    const int arow = r0 + m;
    const bool rowok = arow < N;
    const float* xp = X + (size_t)arow * D + q * 8;

    f32x4 acc[8] = {};
#pragma unroll
    for (int s = 0; s < 4; ++s) {
        float4 xa = {0, 0, 0, 0}, xb = {0, 0, 0, 0};
        if (rowok) {
            xa = *(const float4*)(xp + s * 32);
            xb = *(const float4*)(xp + s * 32 + 4);
        }
        bf16x8 af;
        af[0] = f2bf(xa.x); af[1] = f2bf(xa.y); af[2] = f2bf(xa.z); af[3] = f2bf(xa.w);
        af[4] = f2bf(xb.x); af[5] = f2bf(xb.y); af[6] = f2bf(xb.z); af[7] = f2bf(xb.w);
#pragma unroll
        for (int t = 0; t < 8; ++t) {
            bf16x8 bf = *(const bf16x8*)((const short*)bw + ((s * 8 + t) * 64 + lane) * 8);
            acc[t] = __builtin_amdgcn_mfma_f32_16x16x32_bf16(af, bf, acc[t], 0, 0, 0);
        }
    }
    // C layout: col = lane&15, row = (lane>>4)*4 + i   (verified m89/m91)
#pragma unroll
    for (int t = 0; t < 8; ++t) {
#pragma unroll
        for (int i = 0; i < 4; ++i) {
            const int row = r0 + q * 4 + i;
            if (row < N) h[(size_t)row * D + t * 16 + m] = __float2bfloat16(acc[t][i]);
        }
    }
}

// one wave per node: s1[n] = h[n]·a[0:128], s2[n] = h[n]·a[128:256]
__global__ __launch_bounds__(256) void node_scores(const __hip_bfloat16* __restrict__ h,
                                                   const float* __restrict__ a,
                                                   float* __restrict__ s1,
                                                   float* __restrict__ s2, int N) {
    const int n    = blockIdx.x * 4 + (threadIdx.x >> 6);
    const int lane = threadIdx.x & 63;
    if (n >= N) return;
    const __hip_bfloat162* h2 = (const __hip_bfloat162*)(h + (size_t)n * D);
    const float2* a1 = (const float2*)a;
    const float2* a2 = (const float2*)(a + D);
    float2 hv = __bfloat1622float2(h2[lane]);
    float2 v1 = a1[lane];
    float2 v2 = a2[lane];
    float p1 = hv.x * v1.x + hv.y * v1.y;
    float p2 = hv.x * v2.x + hv.y * v2.y;
#pragma unroll
    for (int off = 32; off > 0; off >>= 1) {
        p1 += __shfl_xor(p1, off);
        p2 += __shfl_xor(p2, off);
    }
    if (lane == 0) { s1[n] = p1; s2[n] = p2; }
}

// histogram of src
__global__ __launch_bounds__(256) void count_edges(const int* __restrict__ src,
                                                   int* __restrict__ counts, int E) {
    const int e = blockIdx.x * 256 + threadIdx.x;
    if (e < E) atomicAdd(&counts[src[e]], 1);
}

// --- hierarchical exclusive scan over counts[N] -> offsets[N] ---
// pass 1: each block scans its 1024-chunk, writes local-exclusive offsets + block total
__global__ __launch_bounds__(256) void scan_block(const int* __restrict__ counts,
                                                  int* __restrict__ offsets,
                                                  int* __restrict__ blocksums, int N) {
    __shared__ int lsum[256];
    const int b = blockIdx.x, t = threadIdx.x;
    const int i0 = b * 1024 + t * 4;
    int c[4];
#pragma unroll
    for (int j = 0; j < 4; ++j) c[j] = (i0 + j < N) ? counts[i0 + j] : 0;
    lsum[t] = c[0] + c[1] + c[2] + c[3];
    __syncthreads();
    for (int off = 1; off < 256; off <<= 1) {
        int v = (t >= off) ? lsum[t - off] : 0;
        __syncthreads();
        lsum[t] += v;
        __syncthreads();
    }
    int run = (t == 0) ? 0 : lsum[t - 1];
#pragma unroll
    for (int j = 0; j < 4; ++j) {
        if (i0 + j < N) offsets[i0 + j] = run;
        run += c[j];
    }
    if (t == 255) blocksums[b] = lsum[255];
}

// pass 2: single block scans the (<=256) block sums -> exclusive block prefixes
__global__ __launch_bounds__(256) void scan_top(const int* __restrict__ blocksums,
                                                int* __restrict__ blockpref, int G) {
    __shared__ int lsum[256];
    const int t = threadIdx.x;
    int v = (t < G) ? blocksums[t] : 0;
    lsum[t] = v;
    __syncthreads();
    for (int off = 1; off < 256; off <<= 1) {
        int u = (t >= off) ? lsum[t - off] : 0;
        __syncthreads();
        lsum[t] += u;
        __syncthreads();
    }
    if (t < G) blockpref[t] = lsum[t] - v;   // exclusive
}

// pass 3: add block prefixes back
__global__ __launch_bounds__(256) void scan_add(int* __restrict__ offsets,
                                                const int* __restrict__ blockpref, int N) {
    const int b = blockIdx.x, t = threadIdx.x;
    const int base = blockpref[b];
    const int i0 = b * 1024 + t * 4;
#pragma unroll
    for (int j = 0; j < 4; ++j)
        if (i0 + j < N) offsets[i0 + j] += base;
}

// scatter (dst, edge_e) into CSR; consumes offsets via atomicAdd
// (post-scatter, offsets[n] == inclusive prefix == start of node n+1)
__global__ __launch_bounds__(256) void scatter_edges(
    const int* __restrict__ src, const int* __restrict__ dst,
    const float* __restrict__ s1, const float* __restrict__ s2,
    int* __restrict__ offsets, int2* __restrict__ csr, int E) {
    const int e = blockIdx.x * 256 + threadIdx.x;
    if (e >= E) return;
    const int s = src[e];
    const int d = dst[e];
    float sc = s1[s] + s2[d];
    sc = sc > 0.f ? sc : 0.2f * sc;       // LeakyReLU(0.2)
    const float ee = __expf(sc);
    const int pos = atomicAdd(&offsets[s], 1);
    csr[pos] = make_int2(d, __float_as_int(ee));
}

// one wave per node: gather-aggregate + fused rowsum-div + ELU
__global__ __launch_bounds__(256) void aggregate(
    const int2* __restrict__ csr, const int* __restrict__ offsets,
    const __hip_bfloat16* __restrict__ h, float* __restrict__ out, int N) {
    const int n    = blockIdx.x * 4 + (threadIdx.x >> 6);
    const int lane = threadIdx.x & 63;
    if (n >= N) return;
    const int beg = (n == 0) ? 0 : offsets[n - 1];
    const int end = offsets[n];
    float2 acc = make_float2(0.f, 0.f);
    float rs = 0.f;
    int k = beg;
    for (; k + 1 < end; k += 2) {
        int2 e0 = csr[k];
        int2 e1 = csr[k + 1];
        const __hip_bfloat162* p0 = (const __hip_bfloat162*)(h + (size_t)e0.x * D);
        const __hip_bfloat162* p1 = (const __hip_bfloat162*)(h + (size_t)e1.x * D);
        __hip_bfloat162 v0 = p0[lane];
        __hip_bfloat162 v1 = p1[lane];
        float ee0 = __int_as_float(e0.y);
        float ee1 = __int_as_float(e1.y);
        float2 f0 = __bfloat1622float2(v0);
        float2 f1 = __bfloat1622float2(v1);
        acc.x += ee0 * f0.x + ee1 * f1.x;
        acc.y += ee0 * f0.y + ee1 * f1.y;
        rs    += ee0 + ee1;
    }
    if (k < end) {
        int2 e0 = csr[k];
        const __hip_bfloat162* p0 = (const __hip_bfloat162*)(h + (size_t)e0.x * D);
        float2 f0 = __bfloat1622float2(p0[lane]);
        float ee0 = __int_as_float(e0.y);
        acc.x += ee0 * f0.x;
        acc.y += ee0 * f0.y;
        rs    += ee0;
    }
    float vx = acc.x / rs;
    float vy = acc.y / rs;
    vx = vx > 0.f ? vx : expm1f(vx);
    vy = vy > 0.f ? vy : expm1f(vy);
    ((float2*)(out + (size_t)n * D))[lane] = make_float2(vx, vy);
}

extern "C" void kernel_launch(void* const* d_in, const int* in_sizes, int n_in,
                              void* d_out, int out_size, void* d_ws, size_t ws_size,
                              hipStream_t stream) {
    const float* X    = (const float*)d_in[0];
    const int*   edge = (const int*)d_in[1];   // [2, E] int32
    const float* W    = (const float*)d_in[2];
    const float* a    = (const float*)d_in[3];
    float* out = (float*)d_out;

    const int N = in_sizes[0] / D;
    const int E = in_sizes[1] / 2;
    const int* src = edge;
    const int* dst = edge + E;

    // workspace layout (16B-aligned slabs): ~19 MB total
    char* ws = (char*)d_ws;
    __hip_bfloat16* h  = (__hip_bfloat16*)ws; ws += (size_t)N * D * sizeof(__hip_bfloat16); // 12.8 MB, 16B-aligned
    int2* csr          = (int2*)ws;  ws += (size_t)E * sizeof(int2);                        // 5.52 MB, stays 16B-aligned
    __hip_bfloat16* bw = (__hip_bfloat16*)ws; ws += 2048 * 8 * sizeof(__hip_bfloat16);      // 32 KB B-frag table (16B-aligned)
    float* s1    = (float*)ws; ws += (size_t)N * sizeof(float);
    float* s2    = (float*)ws; ws += (size_t)N * sizeof(float);
    int* counts  = (int*)ws;   ws += (size_t)N * sizeof(int);
    int* offsets = (int*)ws;   ws += (size_t)(N + 1) * sizeof(int);
    int* blocksums = (int*)ws; ws += 256 * sizeof(int);
    int* blockpref = (int*)ws; ws += 256 * sizeof(int);

    const int Gs = (N + 1023) / 1024;   // scan blocks (49 for N=50000)

    hipMemsetAsync(counts, 0, (size_t)N * sizeof(int), stream);

    prep_w<<<8, 256, 0, stream>>>(W, bw);
    gemm_mfma<<<(N + 63) / 64, 256, 0, stream>>>(X, bw, h, N);
    node_scores<<<(N + 3) / 4, 256, 0, stream>>>(h, a, s1, s2, N);
    count_edges<<<(E + 255) / 256, 256, 0, stream>>>(src, counts, E);
    scan_block<<<Gs, 256, 0, stream>>>(counts, offsets, blocksums, N);
    scan_top<<<1, 256, 0, stream>>>(blocksums, blockpref, Gs);
    scan_add<<<Gs, 256, 0, stream>>>(offsets, blockpref, N);
    scatter_edges<<<(E + 255) / 256, 256, 0, stream>>>(src, dst, s1, s2, offsets, csr, E);
    aggregate<<<(N + 3) / 4, 256, 0, stream>>>(csr, offsets, h, out, N);
}

// Round 5
// 201.349 us; speedup vs baseline: 3.8474x; 1.0885x over previous
//
#include <hip/hip_runtime.h>
#include <hip/hip_bf16.h>

// Sparse GAT layer, gather-based:
//   h = X @ W  via bf16 MFMA (W pre-packed to B-frags); s1/s2 fused in epilogue
//   CSR build by src: histogram -> 2-level scan (add-back fused into consumers)
//   scatter (dst, ee) pairs; per-node wave gather with 16-lane rows, 4 edges/iter
//   out = elu(h'/rs) fused into the gather epilogue

constexpr int D = 128;

typedef __attribute__((ext_vector_type(8))) short bf16x8;   // 8 bf16 = 4 VGPRs
typedef __attribute__((ext_vector_type(4))) float f32x4;

__device__ __forceinline__ short f2bf(float f) {
    unsigned u = __float_as_uint(f);
    unsigned r = (u + 0x7fffu + ((u >> 16) & 1u)) >> 16;    // RNE
    return (short)r;
}
__device__ __forceinline__ float bf2f(short b) {
    return __uint_as_float(((unsigned)(unsigned short)b) << 16);
}

// Pack W into B-fragment order for mfma_f32_16x16x32_bf16:
// bw[((s*8 + t)*64 + lane)*8 + j] = W[k][n],  k = s*32 + (lane>>4)*8 + j,
//                                            n = t*16 + (lane&15)
__global__ __launch_bounds__(256) void prep_w(const float* __restrict__ W,
                                              short* __restrict__ bw) {
    const int tid = blockIdx.x * 256 + threadIdx.x;   // 2048 lane-slots
    if (tid >= 2048) return;
    const int l = tid & 63, st = tid >> 6;
    const int s = st >> 3, t = st & 7;
    const int n = t * 16 + (l & 15);
    const int q = l >> 4;
#pragma unroll
    for (int j = 0; j < 8; ++j) {
        const int k = s * 32 + q * 8 + j;
        bw[tid * 8 + j] = f2bf(W[k * D + n]);
    }
}

// One wave = 16 rows x 128 cols. 4 k-steps x 8 n-tiles of 16x16x32 MFMA.
// Epilogue additionally computes s1[row]=h_bf16[row]·a[:128], s2=·a[128:]
// via in-register reduction (h as-rounded-to-bf16, matching the aggregate input).
__global__ __launch_bounds__(256) void gemm_mfma(const float* __restrict__ X,
                                                 const short* __restrict__ bw,
                                                 const float* __restrict__ a,
                                                 short* __restrict__ h,
                                                 float* __restrict__ s1,
                                                 float* __restrict__ s2, int N) {
    const int wave = threadIdx.x >> 6, lane = threadIdx.x & 63;
    const int r0 = blockIdx.x * 64 + wave * 16;
    const int m = lane & 15, q = lane >> 4;
    const int arow = r0 + m;
    const bool rowok = arow < N;
    const float* xp = X + (size_t)arow * D + q * 8;

    f32x4 acc[8] = {};
#pragma unroll
    for (int s = 0; s < 4; ++s) {
        float4 xa = {0, 0, 0, 0}, xb = {0, 0, 0, 0};
        if (rowok) {
            xa = *(const float4*)(xp + s * 32);
            xb = *(const float4*)(xp + s * 32 + 4);
        }
        bf16x8 af;
        af[0] = f2bf(xa.x); af[1] = f2bf(xa.y); af[2] = f2bf(xa.z); af[3] = f2bf(xa.w);
        af[4] = f2bf(xb.x); af[5] = f2bf(xb.y); af[6] = f2bf(xb.z); af[7] = f2bf(xb.w);
#pragma unroll
        for (int t = 0; t < 8; ++t) {
            bf16x8 bf = *(const bf16x8*)(bw + ((s * 8 + t) * 64 + lane) * 8);
            acc[t] = __builtin_amdgcn_mfma_f32_16x16x32_bf16(af, bf, acc[t], 0, 0, 0);
        }
    }
    // per-lane a1/a2 values for this lane's columns (c = t*16 + m)
    float a1v[8], a2v[8];
#pragma unroll
    for (int t = 0; t < 8; ++t) {
        a1v[t] = a[t * 16 + m];
        a2v[t] = a[D + t * 16 + m];
    }
    // C layout: col = t*16 + (lane&15), row = r0 + (lane>>4)*4 + i
    float p1[4] = {0, 0, 0, 0}, p2[4] = {0, 0, 0, 0};
#pragma unroll
    for (int t = 0; t < 8; ++t) {
#pragma unroll
        for (int i = 0; i < 4; ++i) {
            const int row = r0 + q * 4 + i;
            const short hb = f2bf(acc[t][i]);
            if (row < N) h[(size_t)row * D + t * 16 + m] = hb;   // raw bf16 bits
            const float hr = bf2f(hb);
            p1[i] += hr * a1v[t];
            p2[i] += hr * a2v[t];
        }
    }
    // reduce p1/p2 across the 16 lanes of this quad (same q, all m)
#pragma unroll
    for (int off = 1; off < 16; off <<= 1) {
#pragma unroll
        for (int i = 0; i < 4; ++i) {
            p1[i] += __shfl_xor(p1[i], off);
            p2[i] += __shfl_xor(p2[i], off);
        }
    }
    if (m < 4) {
        const int row = r0 + q * 4 + m;
        if (row < N) {
            const float v1 = (m == 0) ? p1[0] : (m == 1) ? p1[1] : (m == 2) ? p1[2] : p1[3];
            const float v2 = (m == 0) ? p2[0] : (m == 1) ? p2[1] : (m == 2) ? p2[2] : p2[3];
            s1[row] = v1;
            s2[row] = v2;
        }
    }
}

// histogram of src
__global__ __launch_bounds__(256) void count_edges(const int* __restrict__ src,
                                                   int* __restrict__ counts, int E) {
    const int e = blockIdx.x * 256 + threadIdx.x;
    if (e < E) atomicAdd(&counts[src[e]], 1);
}

// pass 1: each block scans its 1024-chunk (local-exclusive) + block total
__global__ __launch_bounds__(256) void scan_block(const int* __restrict__ counts,
                                                  int* __restrict__ offsets,
                                                  int* __restrict__ blocksums, int N) {
    __shared__ int lsum[256];
    const int b = blockIdx.x, t = threadIdx.x;
    const int i0 = b * 1024 + t * 4;
    int c[4];
#pragma unroll
    for (int j = 0; j < 4; ++j) c[j] = (i0 + j < N) ? counts[i0 + j] : 0;
    lsum[t] = c[0] + c[1] + c[2] + c[3];
    __syncthreads();
    for (int off = 1; off < 256; off <<= 1) {
        int v = (t >= off) ? lsum[t - off] : 0;
        __syncthreads();
        lsum[t] += v;
        __syncthreads();
    }
    int run = (t == 0) ? 0 : lsum[t - 1];
#pragma unroll
    for (int j = 0; j < 4; ++j) {
        if (i0 + j < N) offsets[i0 + j] = run;
        run += c[j];
    }
    if (t == 255) blocksums[b] = lsum[255];
}

// pass 2: single block scans (<=256) block sums -> exclusive block prefixes
__global__ __launch_bounds__(256) void scan_top(const int* __restrict__ blocksums,
                                                int* __restrict__ blockpref, int G) {
    __shared__ int lsum[256];
    const int t = threadIdx.x;
    int v = (t < G) ? blocksums[t] : 0;
    lsum[t] = v;
    __syncthreads();
    for (int off = 1; off < 256; off <<= 1) {
        int u = (t >= off) ? lsum[t - off] : 0;
        __syncthreads();
        lsum[t] += u;
        __syncthreads();
    }
    if (t < G) blockpref[t] = lsum[t] - v;   // exclusive
}

// scatter (dst, edge_e) into CSR. Global pos = local atomic + block prefix.
// (post-scatter, offsets[n] == local inclusive prefix)
__global__ __launch_bounds__(256) void scatter_edges(
    const int* __restrict__ src, const int* __restrict__ dst,
    const float* __restrict__ s1, const float* __restrict__ s2,
    int* __restrict__ offsets, const int* __restrict__ blockpref,
    int2* __restrict__ csr, int E) {
    const int e = blockIdx.x * 256 + threadIdx.x;
    if (e >= E) return;
    const int s = src[e];
    const int d = dst[e];
    float sc = s1[s] + s2[d];
    sc = sc > 0.f ? sc : 0.2f * sc;       // LeakyReLU(0.2)
    const float ee = __expf(sc);
    const int pos = atomicAdd(&offsets[s], 1) + blockpref[s >> 10];
    csr[pos] = make_int2(d, __float_as_int(ee));
}

// one wave per node, 16 lanes per row, 4 edges per iteration.
// lane = g*16 + m: group g handles edge k0+g, cols m*8..m*8+7 (one bf16x8 load).
__global__ __launch_bounds__(256) void aggregate(
    const int2* __restrict__ csr, const int* __restrict__ offsets,
    const int* __restrict__ blockpref,
    const short* __restrict__ h, float* __restrict__ out, int N) {
    const int n    = blockIdx.x * 4 + (threadIdx.x >> 6);
    const int lane = threadIdx.x & 63;
    if (n >= N) return;
    const int g = lane >> 4, m = lane & 15;
    const int beg = (n == 0) ? 0 : offsets[n - 1] + blockpref[(n - 1) >> 10];
    const int end = offsets[n] + blockpref[n >> 10];

    float acc[8] = {};
    float rs = 0.f;
    for (int k0 = beg; k0 < end; k0 += 4) {
        const int idx = k0 + g;
        const int2 e  = csr[min(idx, end - 1)];
        const float ee = (idx < end) ? __int_as_float(e.y) : 0.f;
        const bf16x8 row = *(const bf16x8*)(h + (size_t)e.x * D + m * 8);
#pragma unroll
        for (int j = 0; j < 8; ++j)
            acc[j] += ee * bf2f(row[j]);
        rs += ee;
    }
    // combine the 4 edge-groups (lanes l, l^16, l^32, l^48 share the same m)
#pragma unroll
    for (int off = 16; off <= 32; off <<= 1) {
        rs += __shfl_xor(rs, off);
#pragma unroll
        for (int j = 0; j < 8; ++j) acc[j] += __shfl_xor(acc[j], off);
    }
    if (g == 0) {
        const float inv = 1.f / rs;   // every node has a self-loop => rs > 0
        float o[8];
#pragma unroll
        for (int j = 0; j < 8; ++j) {
            float v = acc[j] * inv;
            o[j] = v > 0.f ? v : expm1f(v);
        }
        float* op = out + (size_t)n * D + m * 8;
        *(float4*)op       = make_float4(o[0], o[1], o[2], o[3]);
        *(float4*)(op + 4) = make_float4(o[4], o[5], o[6], o[7]);
    }
}

extern "C" void kernel_launch(void* const* d_in, const int* in_sizes, int n_in,
                              void* d_out, int out_size, void* d_ws, size_t ws_size,
                              hipStream_t stream) {
    const float* X    = (const float*)d_in[0];
    const int*   edge = (const int*)d_in[1];   // [2, E] int32
    const float* W    = (const float*)d_in[2];
    const float* a    = (const float*)d_in[3];
    float* out = (float*)d_out;

    const int N = in_sizes[0] / D;
    const int E = in_sizes[1] / 2;
    const int* src = edge;
    const int* dst = edge + E;

    // workspace layout (16B-aligned slabs): ~19 MB total
    char* ws = (char*)d_ws;
    short* h     = (short*)ws; ws += (size_t)N * D * sizeof(short);   // 12.8 MB (bf16 bits)
    int2* csr    = (int2*)ws;  ws += (size_t)E * sizeof(int2);        // 5.52 MB
    short* bw    = (short*)ws; ws += 2048 * 8 * sizeof(short);        // 32 KB B-frag table
    float* s1    = (float*)ws; ws += (size_t)N * sizeof(float);
    float* s2    = (float*)ws; ws += (size_t)N * sizeof(float);
    int* counts  = (int*)ws;   ws += (size_t)N * sizeof(int);
    int* offsets = (int*)ws;   ws += (size_t)(N + 1) * sizeof(int);
    int* blocksums = (int*)ws; ws += 256 * sizeof(int);
    int* blockpref = (int*)ws; ws += 256 * sizeof(int);

    const int Gs = (N + 1023) / 1024;   // scan blocks (49 for N=50000)

    (void)hipMemsetAsync(counts, 0, (size_t)N * sizeof(int), stream);

    prep_w<<<8, 256, 0, stream>>>(W, bw);
    gemm_mfma<<<(N + 63) / 64, 256, 0, stream>>>(X, bw, a, h, s1, s2, N);
    count_edges<<<(E + 255) / 256, 256, 0, stream>>>(src, counts, E);
    scan_block<<<Gs, 256, 0, stream>>>(counts, offsets, blocksums, N);
    scan_top<<<1, 256, 0, stream>>>(blocksums, blockpref, Gs);
    scatter_edges<<<(E + 255) / 256, 256, 0, stream>>>(src, dst, s1, s2, offsets, blockpref, csr, E);
    aggregate<<<(N + 3) / 4, 256, 0, stream>>>(csr, offsets, blockpref, h, out, N);
}